// Round 5
// baseline (338.403 us; speedup 1.0000x reference)
//
#include <hip/hip_runtime.h>
#include <stdint.h>

// SNN forward with STP/STDP, delays {1,2,3,5}, B=8 T=64 NI=256 N=512 NO=32 D=4.
// Persistent dataflow kernel: 512 blocks = 8 batches x 64 o-chunks (8 o's), 128 thr.
// 2 blocks/CU guaranteed co-resident (LDS 37KB, 4 waves) -> latency overlap.
// Lane mapping: e_grp = lane>>2 (16/wave), o = wave*4 + (lane&3) -> e-reduction is
// wave-local shuffles; ONE barrier per step (double-buffered LDS delay planes).
// Timing discipline (R4 lesson): publish rec(t+1) at END of iter t (a FULL iteration
// before any consumer stages it); issue ALL delay prefetches at TOP of the iteration
// (a full phase-C of flight time). Sentinel retries should now be rare.
// Cross-block recurrence: packed 8B records {syn_p, xbar|spikebit}, relaxed
// AGENT-scope atomics, 0xFFFFFFFF-hi sentinel as data-ready flag (no fences).

#define B  8
#define T  64
#define NI 256
#define NN 512
#define NO 32
#define DD 4

#define NBLK 512
#define TPB  128
#define OPB  8           // o's per block
#define SPL  32          // synapses per lane
#define EPAD 516         // padded per-d LDS plane stride (float2 elems)
#define PLANE (DD*EPAD)  // one buffer = 4 planes

#define REC_ELEMS (T*B*NN)

__device__ __forceinline__ unsigned long long rec_load(const unsigned long long* p) {
    return __hip_atomic_load(p, __ATOMIC_RELAXED, __HIP_MEMORY_SCOPE_AGENT);
}
__device__ __forceinline__ void rec_store(unsigned long long* p, unsigned long long v) {
    __hip_atomic_store(p, v, __ATOMIC_RELAXED, __HIP_MEMORY_SCOPE_AGENT);
}
__device__ __forceinline__ bool is_sentinel(unsigned long long v) {
    return (unsigned int)(v >> 32) == 0xFFFFFFFFu;   // impossible xbar bit pattern
}
__device__ __forceinline__ float2 unpack_rec(unsigned long long v) {
    return make_float2(__uint_as_float((unsigned int)v),
                       __uint_as_float((unsigned int)(v >> 32)));  // keep -0.0 sign!
}

__global__ __launch_bounds__(TPB, 1)
void snn_main(const float* __restrict__ inputs,
              const float* __restrict__ w,
              const float* __restrict__ w_in,
              const float* __restrict__ dmap,
              const int*   __restrict__ delays,
              const float* __restrict__ w_signs,
              const float* __restrict__ p,
              const float* __restrict__ A_p,
              const float* __restrict__ A_d,
              const float* __restrict__ w_out,
              unsigned long long* __restrict__ rec,
              float* __restrict__ out)
{
    __shared__ float2 sxq[2*PLANE];     // double-buffered delay planes, 33 KB
    __shared__ float  inp_s[T*OPB];     // 2 KB per-block input currents
    __shared__ float  hist[T][OPB];     // 2 KB spike history for fused readout

    const int tid     = threadIdx.x;
    const int bid     = blockIdx.x;
    const int b       = bid & 7;
    const int chunk   = bid >> 3;
    const int o_base  = chunk * OPB;
    const int lane    = tid & 63;
    const int wave    = tid >> 6;
    const int e_grp   = lane >> 2;               // 0..15, within one wave
    const int o_local = wave*4 + (lane & 3);     // 4 o's per wave, 8 per block
    const int o       = o_base + o_local;
    const bool pub    = (e_grp == 0);            // 8 publishers, one per o

    // publish slot 0 (zero record) FIRST: t=1 staging of other blocks never waits long
    if (tid < OPB) rec_store(rec + (size_t)(0*B + b)*NN + o_base + tid, 0ull);

    // ---------------- per-lane synapse constants (registers) -----------------
    float wv[SPL], ap[SPL], ad[SPL], ws[SPL];
    int   laddr[SPL];
    #pragma unroll
    for (int i = 0; i < SPL; ++i) {
        const int e = e_grp + 16*i;
        wv[i] = w_signs[e] * fabsf(w[e*NN + o]);
        ap[i] = A_p[e*NN + o];
        ad[i] = A_d[e*NN + o];
        int d = 0;
        if (dmap[1*NN*NN + e*NN + o] != 0.0f) d = 1;
        if (dmap[2*NN*NN + e*NN + o] != 0.0f) d = 2;
        if (dmap[3*NN*NN + e*NN + o] != 0.0f) d = 3;
        ws[i]    = 1.0f;
        laddr[i] = (d*EPAD + e) * 8;             // byte offset within a buffer
    }
    int del[DD];
    #pragma unroll
    for (int d = 0; d < DD; ++d) del[d] = delays[d];

    // ---------------- prologue: inp[b,t,o] slice = inputs @ w_in -------------
    {
        float* win = (float*)sxq;                // 2048-float alias, prologue-only
        for (int k = tid; k < NI*OPB; k += TPB) {
            const int c = k >> 3, oo = k & 7;
            win[c*OPB + oo] = w_in[c*NN + o_base + oo];
        }
        __syncthreads();
        const int prow = tid >> 3, pcol = tid & 7;   // 16 row-groups x 8 cols
        #pragma unroll
        for (int j = 0; j < 4; ++j) {
            const int tj = prow*4 + j;
            const float* inrow = inputs + (size_t)(b*T + tj)*NI;
            float a = 0.f;
            for (int c = 0; c < NI; ++c) a += inrow[c] * win[c*OPB + pcol];
            inp_s[tj*OPB + pcol] = a;
        }
        __syncthreads();
    }

    // zero-fill buffer 0 for step 0 (all delays > 0 => all gathered slots zero)
    #pragma unroll
    for (int d = 0; d < DD; ++d)
        #pragma unroll
        for (int k = 0; k < 4; ++k)
            sxq[d*EPAD + k*TPB + tid] = make_float2(0.f, 0.f);
    __syncthreads();

    float mem = 0.f, w_p = 0.f, x_bar = 0.f, u_pot = 0.f, u_dep = 0.f;
    const float p_o  = p[o];
    const float pd_o = (p_o < 0.f) ? 1.f : 0.f;

    unsigned long long pf[DD][4];

    for (int t = 0; t < T; ++t) {
        // ---- 1. prefetch ALL delay planes for step t+1 (every source record was
        //         published >= one full iteration ago -> almost always ready) ----
        if (t + 1 < T) {
            #pragma unroll
            for (int d = 0; d < DD; ++d) {
                if (t + 1 >= del[d]) {
                    const int s = (t + 1 - del[d]) & 63;
                    const unsigned long long* src = rec + (size_t)(s*B + b)*NN + tid;
                    #pragma unroll
                    for (int k = 0; k < 4; ++k) pf[d][k] = rec_load(src + k*TPB);
                }
            }
        }

        // ---- 2. spike + gates (pre-update state); spike history for readout ----
        const float spike = (mem > 1.0f) ? 1.0f : 0.0f;
        if (pub) hist[t][o_local] = spike;
        const float pg  = spike * fmaxf(u_pot, 0.f);
        const float udr = fmaxf(u_dep, 0.f);

        // ---- 3. phase C: 32 synapses/lane over current buffer ----
        const char* cbuf = (const char*)sxq + (t & 1)*(PLANE*8);
        float acc = 0.f;
        #pragma unroll
        for (int i = 0; i < SPL; ++i) {
            const float2 v = *(const float2*)(cbuf + laddr[i]);
            acc = fmaf(v.x, wv[i]*ws[i], acc);              // syn uses OLD w_stdp
            const unsigned int xu = __float_as_uint(v.y);
            const float dep = ((int)xu < 0) ? ad[i]*udr : 0.f;
            const float pot = (ap[i]*pg) * fabsf(v.y);
            ws[i] = fminf(fmaxf(ws[i] + pot - dep, 0.f), 2.f);
        }

        // ---- 4. wave-local e-reduction: quad tree then ((P0+P1)+P2)+P3 ----
        float a2 = acc + __shfl_xor(acc, 4);
        a2 += __shfl_xor(a2, 8);                            // quad q=lane>>4 holds P_q
        const int src0 = lane & 15;
        const float p0 = __shfl(a2, src0);
        const float p1 = __shfl(a2, src0 + 16);
        const float p2 = __shfl(a2, src0 + 32);
        const float p3 = __shfl(a2, src0 + 48);
        const float syn = ((p0 + p1) + p2) + p3;

        // ---- 5. state updates (reference order) ----
        const float wp_new = 0.85f*w_p + spike * p_o * (1.f + pd_o*w_p);
        const float xb_new = 0.95f*x_bar + 0.05f*spike;
        u_pot = 0.95f*u_pot + 0.05f*mem;
        u_dep = 0.95f*u_dep + 0.05f*mem;
        mem   = 0.9f*mem + inp_s[t*OPB + o_local] + syn - spike;
        w_p   = wp_new;
        x_bar = xb_new;

        // ---- 6. publish rec(t+1) NOW: a full iteration before anyone stages it ----
        if (t + 1 < T && pub) {
            const float spike1 = (mem > 1.0f) ? 1.0f : 0.0f;
            const float sp = spike1 * (1.f + w_p);
            const unsigned int xu = __float_as_uint(x_bar) | (spike1 != 0.f ? 0x80000000u : 0u);
            rec_store(rec + (size_t)((t+1)*B + b)*NN + o,
                      ((unsigned long long)xu << 32) | (unsigned int)__float_as_uint(sp));
        }

        // ---- 7. stage step t+1 into the other buffer (poll only if unlucky) ----
        if (t + 1 < T) {
            float2* wbuf = sxq + ((t+1) & 1)*PLANE;
            #pragma unroll
            for (int d = 0; d < DD; ++d) {
                if (t + 1 >= del[d]) {
                    const int s = (t + 1 - del[d]) & 63;
                    const unsigned long long* src = rec + (size_t)(s*B + b)*NN + tid;
                    #pragma unroll
                    for (int k = 0; k < 4; ++k) {
                        unsigned long long v = pf[d][k];
                        int guard = 0;
                        while (is_sentinel(v)) {
                            __builtin_amdgcn_s_sleep(1);
                            v = rec_load(src + k*TPB);
                            if (++guard > (1 << 24)) break;   // fail loud, not hung
                        }
                        wbuf[d*EPAD + k*TPB + tid] = unpack_rec(v);
                    }
                } else {
                    #pragma unroll
                    for (int k = 0; k < 4; ++k)
                        wbuf[d*EPAD + k*TPB + tid] = make_float2(0.f, 0.f);
                }
            }
        }
        __syncthreads();   // the ONE barrier: staging + hist visible for t+1
    }

    // ---------------- epilogue: fused readout (h2 + leaky scan) --------------
    if (tid < NO) {
        float wo[OPB];
        #pragma unroll
        for (int j = 0; j < OPB; ++j) wo[j] = w_out[(o_base + j)*NO + tid];
        float st = 0.f;
        for (int t = 0; t < T; ++t) {
            float h = 0.f;
            #pragma unroll
            for (int j = 0; j < OPB; ++j) h = fmaf(hist[t][j], wo[j], h);
            st = 0.9f*st + h;
            atomicAdd(out + ((size_t)b*T + t)*NO + tid, st);  // fire-and-forget
        }
    }
}

extern "C" void kernel_launch(void* const* d_in, const int* in_sizes, int n_in,
                              void* d_out, int out_size, void* d_ws, size_t ws_size,
                              hipStream_t stream)
{
    const float* inputs  = (const float*)d_in[0];
    const float* w       = (const float*)d_in[1];
    const float* w_in    = (const float*)d_in[2];
    const float* w_out   = (const float*)d_in[3];
    const float* dmap    = (const float*)d_in[4];
    const int*   delays  = (const int*)  d_in[5];
    const float* w_signs = (const float*)d_in[6];
    const float* p       = (const float*)d_in[7];
    const float* A_p     = (const float*)d_in[8];
    const float* A_d     = (const float*)d_in[9];

    unsigned long long* rec = (unsigned long long*)d_ws;   // 2 MB packed records
    float* out = (float*)d_out;

    hipMemsetAsync(rec, 0xFF, (size_t)REC_ELEMS*8, stream);   // sentinel-fill
    hipMemsetAsync(out, 0, (size_t)B*T*NO*4, stream);         // atomicAdd target

    hipLaunchKernelGGL(snn_main, dim3(NBLK), dim3(TPB), 0, stream,
                       inputs, w, w_in, dmap, delays, w_signs, p, A_p, A_d,
                       w_out, rec, out);
}

// Round 7
// 278.119 us; speedup vs baseline: 1.2168x; 1.2168x over previous
//
#include <hip/hip_runtime.h>
#include <stdint.h>

// SNN forward with STP/STDP, delays {1,2,3,5}, B=8 T=64 NI=256 N=512 NO=32 D=4.
// Persistent dataflow kernel: 256 blocks = 8 batches x 32 o-chunks (16 o's), 256 thr.
// == R4 schedule (empirically replay-stable at 215us) + two hardenings ==
//  1. rec loads/stores at SYSTEM scope: sc0+sc1 force every access past the
//     non-coherent L1/XCD-L2 to the MALL coherence point. Closes the
//     cross-replay stale-line window (stale L2 line with last replay's
//     valid-looking record would defeat the sentinel check).
//  2. __atomic_signal_fence(SEQ_CST) around the publish store and retry loads:
//     compiler-only fences (no HW instructions) pinning relaxed-atomic issue
//     points so the optimizer cannot sink/hoist them across the schedule.
// Event schedule (R4): publish rec(t) at TOP of iter t (ack drains during phase
// C); delay-1 fetch of rec(t) right AFTER phase C; delay>=2 prefetch at top.
// Sentinel protocol: hi-word 0xFFFFFFFF (impossible xbar bits) = unwritten.

#define B  8
#define T  64
#define NI 256
#define NN 512
#define NO 32
#define DD 4

#define NBLK 256
#define TPB  256
#define OPB  16          // o's per block
#define SPL  32          // synapses per lane
#define EPAD 516         // padded per-d LDS plane stride (float2 elems)
#define PLANE (DD*EPAD)  // one buffer = 4 planes

#define REC_ELEMS (T*B*NN)

__device__ __forceinline__ unsigned long long rec_load(const unsigned long long* p) {
    return __hip_atomic_load(p, __ATOMIC_RELAXED, __HIP_MEMORY_SCOPE_SYSTEM);
}
__device__ __forceinline__ void rec_store(unsigned long long* p, unsigned long long v) {
    __atomic_signal_fence(__ATOMIC_SEQ_CST);   // pin issue point (compiler-only)
    __hip_atomic_store(p, v, __ATOMIC_RELAXED, __HIP_MEMORY_SCOPE_SYSTEM);
    __atomic_signal_fence(__ATOMIC_SEQ_CST);
}
__device__ __forceinline__ bool is_sentinel(unsigned long long v) {
    return (unsigned int)(v >> 32) == 0xFFFFFFFFu;   // impossible xbar bit pattern
}
__device__ __forceinline__ float2 unpack_rec(unsigned long long v) {
    return make_float2(__uint_as_float((unsigned int)v),
                       __uint_as_float((unsigned int)(v >> 32)));  // keep -0.0 sign!
}

__global__ __launch_bounds__(TPB, 1)
void snn_main(const float* __restrict__ inputs,
              const float* __restrict__ w,
              const float* __restrict__ w_in,
              const float* __restrict__ dmap,
              const int*   __restrict__ delays,
              const float* __restrict__ w_signs,
              const float* __restrict__ p,
              const float* __restrict__ A_p,
              const float* __restrict__ A_d,
              const float* __restrict__ w_out,
              unsigned long long* __restrict__ rec,
              float* __restrict__ out)
{
    __shared__ float2 sxq[2*PLANE];     // double-buffered delay planes, 33 KB
    __shared__ float  inp_s[T*OPB];     // 4 KB per-block input currents
    __shared__ float  hist[T][OPB];     // 4 KB spike history for fused readout

    const int tid     = threadIdx.x;
    const int bid     = blockIdx.x;
    const int b       = bid & 7;
    const int chunk   = bid >> 3;
    const int o_base  = chunk * OPB;
    const int lane    = tid & 63;
    const int wave    = tid >> 6;
    const int e_grp   = lane >> 2;               // 0..15, within one wave
    const int o_local = wave*4 + (lane & 3);     // 4 o's per wave, 16 per block
    const int o       = o_base + o_local;
    const bool pub    = (e_grp == 0);            // 16 publishers, one per o

    // publish slot 0 (zero record) FIRST: t=0 staging of other blocks never waits long
    if (tid < OPB) rec_store(rec + (size_t)(0*B + b)*NN + o_base + tid, 0ull);

    // ---------------- per-lane synapse constants (registers) -----------------
    float wv[SPL], ap[SPL], ad[SPL], ws[SPL];
    int   laddr[SPL];
    #pragma unroll
    for (int i = 0; i < SPL; ++i) {
        const int e = e_grp + 16*i;
        wv[i] = w_signs[e] * fabsf(w[e*NN + o]);
        ap[i] = A_p[e*NN + o];
        ad[i] = A_d[e*NN + o];
        int d = 0;
        if (dmap[1*NN*NN + e*NN + o] != 0.0f) d = 1;
        if (dmap[2*NN*NN + e*NN + o] != 0.0f) d = 2;
        if (dmap[3*NN*NN + e*NN + o] != 0.0f) d = 3;
        ws[i]    = 1.0f;
        laddr[i] = (d*EPAD + e) * 8;             // byte offset within a buffer
    }
    int del[DD];
    #pragma unroll
    for (int d = 0; d < DD; ++d) del[d] = delays[d];

    // ---------------- prologue: inp[b,t,o] slice = inputs @ w_in -------------
    {
        float* win = (float*)sxq;                // 4096-float alias, prologue-only
        for (int k = tid; k < NI*OPB; k += TPB) {
            const int c = k >> 4, oo = k & 15;
            win[c*OPB + oo] = w_in[c*NN + o_base + oo];
        }
        __syncthreads();
        const int prow = tid >> 4, pcol = tid & 15;
        #pragma unroll
        for (int j = 0; j < 4; ++j) {
            const int tj = prow*4 + j;
            const float* inrow = inputs + (size_t)(b*T + tj)*NI;
            float a = 0.f;
            for (int c = 0; c < NI; ++c) a += inrow[c] * win[c*OPB + pcol];
            inp_s[tj*OPB + pcol] = a;
        }
        __syncthreads();
    }

    // zero-fill buffer 0 for step 0 (all delays > 0 => all gathered slots zero)
    #pragma unroll
    for (int d = 0; d < DD; ++d) {
        sxq[d*EPAD + tid]       = make_float2(0.f, 0.f);
        sxq[d*EPAD + 256 + tid] = make_float2(0.f, 0.f);
    }
    __syncthreads();

    float mem = 0.f, w_p = 0.f, x_bar = 0.f, u_pot = 0.f, u_dep = 0.f;
    const float p_o  = p[o];
    const float pd_o = (p_o < 0.f) ? 1.f : 0.f;

    unsigned long long pk = 0ull;        // packed record for rec(t), built at iter t-1
    unsigned long long pf[DD][2];

    for (int t = 0; t < T; ++t) {
        // ---- 1. publish rec(t) at TOP: MALL ack drains during phase C, not at barrier
        if (t >= 1 && pub)
            rec_store(rec + (size_t)(t*B + b)*NN + o, pk);

        // ---- 2. prefetch delay>=2 planes for step t+1 (>=1 iter old: always ready)
        if (t + 1 < T) {
            #pragma unroll
            for (int d = 0; d < DD; ++d) {
                if (del[d] > 1 && t + 1 >= del[d]) {
                    const int s = (t + 1 - del[d]) & 63;
                    const unsigned long long* src = rec + (size_t)(s*B + b)*NN + tid;
                    pf[d][0] = rec_load(src);
                    pf[d][1] = rec_load(src + 256);
                }
            }
        }

        // ---- 3. spike + gates (pre-update state); spike history for readout ----
        const float spike = (mem > 1.0f) ? 1.0f : 0.0f;
        if (pub) hist[t][o_local] = spike;
        const float pg  = spike * fmaxf(u_pot, 0.f);
        const float udr = fmaxf(u_dep, 0.f);

        // ---- 4. phase C: 32 synapses/lane over current buffer ----
        const char* cbuf = (const char*)sxq + (t & 1)*(PLANE*8);
        float acc = 0.f;
        #pragma unroll
        for (int i = 0; i < SPL; ++i) {
            const float2 v = *(const float2*)(cbuf + laddr[i]);
            acc = fmaf(v.x, wv[i]*ws[i], acc);              // syn uses OLD w_stdp
            const unsigned int xu = __float_as_uint(v.y);
            const float dep = ((int)xu < 0) ? ad[i]*udr : 0.f;
            const float pot = (ap[i]*pg) * fabsf(v.y);
            ws[i] = fminf(fmaxf(ws[i] + pot - dep, 0.f), 2.f);
        }

        // ---- 4.5 issue delay-1 loads NOW (rec(t): producers published ~phase-C ago)
        unsigned long long q0 = 0ull, q1 = 0ull;
        if (t + 1 < T) {
            #pragma unroll
            for (int d = 0; d < DD; ++d) {
                if (del[d] == 1) {
                    const unsigned long long* src = rec + (size_t)(t*B + b)*NN + tid;
                    q0 = rec_load(src);
                    q1 = rec_load(src + 256);
                }
            }
        }

        // ---- 5. wave-local e-reduction: quad tree then ((P0+P1)+P2)+P3 ----
        float a2 = acc + __shfl_xor(acc, 4);
        a2 += __shfl_xor(a2, 8);                            // quad q=lane>>4 holds P_q
        const int src0 = lane & 15;
        const float p0 = __shfl(a2, src0);
        const float p1 = __shfl(a2, src0 + 16);
        const float p2 = __shfl(a2, src0 + 32);
        const float p3 = __shfl(a2, src0 + 48);
        const float syn = ((p0 + p1) + p2) + p3;

        // ---- 6. state updates (reference order); build rec(t+1) in registers ----
        const float wp_new = 0.85f*w_p + spike * p_o * (1.f + pd_o*w_p);
        const float xb_new = 0.95f*x_bar + 0.05f*spike;
        u_pot = 0.95f*u_pot + 0.05f*mem;
        u_dep = 0.95f*u_dep + 0.05f*mem;
        mem   = 0.9f*mem + inp_s[t*OPB + o_local] + syn - spike;
        w_p   = wp_new;
        x_bar = xb_new;
        if (t + 1 < T) {
            const float spike1 = (mem > 1.0f) ? 1.0f : 0.0f;
            const float sp = spike1 * (1.f + w_p);
            const unsigned int xu = __float_as_uint(x_bar) | (spike1 != 0.f ? 0x80000000u : 0u);
            pk = ((unsigned long long)xu << 32) | (unsigned int)__float_as_uint(sp);
        }

        // ---- 7. stage step t+1 into the other buffer ----
        if (t + 1 < T) {
            float2* wbuf = sxq + ((t+1) & 1)*PLANE;
            #pragma unroll
            for (int d = 0; d < DD; ++d) {
                unsigned long long v0 = 0ull, v1 = 0ull;
                if (t + 1 >= del[d]) {
                    const int s = (t + 1 - del[d]) & 63;
                    const unsigned long long* src = rec + (size_t)(s*B + b)*NN + tid;
                    if (del[d] == 1) { v0 = q0;       v1 = q1;       }
                    else             { v0 = pf[d][0]; v1 = pf[d][1]; }
                    int guard = 0;
                    while (is_sentinel(v0) || is_sentinel(v1)) {
                        __builtin_amdgcn_s_sleep(1);
                        __atomic_signal_fence(__ATOMIC_SEQ_CST);   // pin reloads here
                        if (is_sentinel(v0)) v0 = rec_load(src);
                        if (is_sentinel(v1)) v1 = rec_load(src + 256);
                        if (++guard > (1 << 24)) break;   // fail loud, not hung
                    }
                }
                wbuf[d*EPAD + tid]       = unpack_rec(v0);
                wbuf[d*EPAD + 256 + tid] = unpack_rec(v1);
            }
        }
        __syncthreads();   // the ONE barrier: staging + hist visible for t+1
    }

    // ---------------- epilogue: fused readout (h2 + leaky scan) --------------
    if (tid < NO) {
        float wo[OPB];
        #pragma unroll
        for (int j = 0; j < OPB; ++j) wo[j] = w_out[(o_base + j)*NO + tid];
        float st = 0.f;
        for (int t = 0; t < T; ++t) {
            float h = 0.f;
            #pragma unroll
            for (int j = 0; j < OPB; ++j) h = fmaf(hist[t][j], wo[j], h);
            st = 0.9f*st + h;
            atomicAdd(out + ((size_t)b*T + t)*NO + tid, st);  // fire-and-forget
        }
    }
}

extern "C" void kernel_launch(void* const* d_in, const int* in_sizes, int n_in,
                              void* d_out, int out_size, void* d_ws, size_t ws_size,
                              hipStream_t stream)
{
    const float* inputs  = (const float*)d_in[0];
    const float* w       = (const float*)d_in[1];
    const float* w_in    = (const float*)d_in[2];
    const float* w_out   = (const float*)d_in[3];
    const float* dmap    = (const float*)d_in[4];
    const int*   delays  = (const int*)  d_in[5];
    const float* w_signs = (const float*)d_in[6];
    const float* p       = (const float*)d_in[7];
    const float* A_p     = (const float*)d_in[8];
    const float* A_d     = (const float*)d_in[9];

    unsigned long long* rec = (unsigned long long*)d_ws;   // 2 MB packed records
    float* out = (float*)d_out;

    hipMemsetAsync(rec, 0xFF, (size_t)REC_ELEMS*8, stream);   // sentinel-fill
    hipMemsetAsync(out, 0, (size_t)B*T*NO*4, stream);         // atomicAdd target

    hipLaunchKernelGGL(snn_main, dim3(NBLK), dim3(TPB), 0, stream,
                       inputs, w, w_in, dmap, delays, w_signs, p, A_p, A_d,
                       w_out, rec, out);
}